// Round 9
// baseline (1018.540 us; speedup 1.0000x reference)
//
#include <hip/hip_runtime.h>
#include <hip/hip_fp16.h>
#include <math.h>

typedef unsigned short u16;
typedef float f32x4 __attribute__((ext_vector_type(4)));
typedef __bf16 bf16x8 __attribute__((ext_vector_type(8)));

__device__ __forceinline__ float b2f(u16 u) {
    union { unsigned int i; float f; } v; v.i = ((unsigned int)u) << 16; return v.f;
}
__device__ __forceinline__ u16 f2b(float f) {
    union { float f; unsigned int i; } v; v.f = f;
    unsigned int lsb = (v.i >> 16) & 1u;
    return (u16)((v.i + 0x7fffu + lsb) >> 16);   // RNE
}
// HW RNE pack: low16 = bf16(lo), high16 = bf16(hi). Bit-identical to f2b.
__device__ __forceinline__ unsigned int cvtpk(float lo, float hi) {
    unsigned int r;
    asm("v_cvt_pk_bf16_f32 %0, %1, %2" : "=v"(r) : "v"(lo), "v"(hi));
    return r;
}

// ---------------------------------------------------------------------------
// CSR build: counts -> block scan -> global scan -> fill
// ---------------------------------------------------------------------------
__global__ __launch_bounds__(256)
void k_scan1(const int* __restrict__ cnt, int* __restrict__ rowptr,
             int* __restrict__ bsum, int N)
{
    __shared__ int s[256];
    int t = threadIdx.x, i = blockIdx.x * 256 + t;
    int v = (i < N) ? cnt[i] : 0;
    s[t] = v;
    __syncthreads();
#pragma unroll
    for (int off = 1; off < 256; off <<= 1) {
        int add = (t >= off) ? s[t - off] : 0;
        __syncthreads();
        s[t] += add;
        __syncthreads();
    }
    if (i < N) rowptr[i] = s[t] - v;
    if (t == 255) bsum[blockIdx.x] = s[255];
}

__global__ __launch_bounds__(256)
void k_scan2(const int* __restrict__ bsum, int* __restrict__ bscan, int nb)
{
    __shared__ int s[256];
    int t = threadIdx.x;
    int g[4], e[4];
    int base = t * 4;
#pragma unroll
    for (int j = 0; j < 4; ++j) g[j] = (base + j < nb) ? bsum[base + j] : 0;
    e[0] = 0; e[1] = g[0]; e[2] = g[0] + g[1]; e[3] = g[0] + g[1] + g[2];
    int tsum = e[3] + g[3];
    s[t] = tsum;
    __syncthreads();
#pragma unroll
    for (int off = 1; off < 256; off <<= 1) {
        int add = (t >= off) ? s[t - off] : 0;
        __syncthreads();
        s[t] += add;
        __syncthreads();
    }
    int texcl = s[t] - tsum;
#pragma unroll
    for (int j = 0; j < 4; ++j)
        if (base + j < nb) bscan[base + j] = texcl + e[j];
}

__global__ __launch_bounds__(256)
void k_scan3(int* __restrict__ rowptr, const int* __restrict__ bscan,
             int* __restrict__ cursor, int N)
{
    int i = blockIdx.x * 256 + threadIdx.x;
    if (i >= N) return;
    int r = rowptr[i] + bscan[i >> 8];
    rowptr[i] = r;
    cursor[i] = r;
}

__global__ __launch_bounds__(256)
void k_fill(const int* __restrict__ src, const int* __restrict__ dst,
            int* __restrict__ cursor, int* __restrict__ col, int E)
{
    int e = blockIdx.x * 256 + threadIdx.x;
    if (e >= E) return;
    int pos = atomicAdd(&cursor[dst[e]], 1);
    col[pos] = src[e];
}

// ---------------------------------------------------------------------------
// Fused setup: edge counting + all 7 weight transposes (f32->bf16) in ONE
// launch. Grid = 1920 blocks x 256 (491520 transpose elems >= 409600 edges).
// ---------------------------------------------------------------------------
__global__ __launch_bounds__(256)
void k_setup(const float* __restrict__ w0a, const float* __restrict__ w0b,
             const float* __restrict__ wra, const float* __restrict__ wrb,
             const float* __restrict__ Wc,  u16* __restrict__ wt,
             const int* __restrict__ dst, int* __restrict__ cnt, int E)
{
    int t = blockIdx.x * 256 + threadIdx.x;
    if (t < E) atomicAdd(&cnt[dst[t]], 1);

    const float* in; u16* out; int K, N, l;
    if      (t < 32768)  { in = w0a;          out = wt;          K = 128; N = 256; l = t; }
    else if (t < 98304)  { in = w0b;          out = wt + 65536;  K = 256; N = 256; l = t - 32768; }
    else if (t < 163840) { in = wra;          out = wt + 131072; K = 256; N = 256; l = t - 98304; }
    else if (t < 229376) { in = wra + 65536;  out = wt + 196608; K = 256; N = 256; l = t - 163840; }
    else if (t < 294912) { in = wrb;          out = wt + 262144; K = 256; N = 256; l = t - 229376; }
    else if (t < 360448) { in = wrb + 65536;  out = wt + 327680; K = 256; N = 256; l = t - 294912; }
    else if (t < 491520) { in = Wc;           out = wt + 393216; K = 256; N = 512; l = t - 360448; }
    else return;
    out[l] = f2b(in[(l % K) * N + l / K]);
}

// ---------------------------------------------------------------------------
// Fused GIN layer v9: v8 + FULL-ROW 2-DEEP gather pipeline.
//
// Gather: all row addresses come from colLDS (no pointer chaining). Rows
// t and t+1 held in registers (A,B); row t+2's loads are ISSUED while row t
// is accumulated, and row t+3's address is computed. The waitcnt for row
// t+2 lands after ~64 VALU ops -> per-iteration load latency hidden.
// Accumulation order per row unchanged (bit-identical numerics).
//
// AH 16B-slot layout: elem(row,k) in slot
//   s = (k>>5)*256 + (row>>4)*64 + ((k>>3)&3)*16 + (row&15), sub-off (k&7)
// Physical slot: sp = s ^ ((k>>5)&7); frag reads use lane ^ (kb&7).
// ---------------------------------------------------------------------------
#define CCAP 512

template<int K, bool RELU, bool F32SRC>
__global__ __launch_bounds__(512, 6)
void k_gin(const void* __restrict__ hsrc,
           const int* __restrict__ cnt, const int* __restrict__ rowptr,
           const int* __restrict__ col,
           const u16* __restrict__ WaT, const float* __restrict__ ba,
           const u16* __restrict__ WbT, const float* __restrict__ bb,
           u16* __restrict__ Hout, int Ntot, int Etot)
{
    __shared__ u16 AH[64 * 256];     // 32 KB = 2048 slots of 16B
    __shared__ int colLDS[CCAP];     //  2 KB

    const int tid = threadIdx.x, lane = tid & 63, wave = tid >> 6;
    const int bm0 = blockIdx.x * 64;
    const int lc = lane & 15, lr = (lane >> 4) * 4;
    const int cw0 = wave * 32;                    // this wave's 32 output cols
    const int l15 = lane & 15, lq = lane >> 4;

    // ---- stage block's col slice into LDS (coalesced) ----
    const int rp0 = rowptr[bm0];
    const int rpE = (bm0 + 64 < Ntot) ? rowptr[bm0 + 64] : Etot;
    const int total = rpE - rp0;
    for (int i = tid; i < total && i < CCAP; i += 512) colLDS[i] = col[rp0 + i];

    // prefetch phase-1 B fragments for kb=0 (independent of gather)
    bf16x8 bpre0 = *(const bf16x8*)(WaT + (size_t)(cw0 + l15) * K + lq * 8);
    bf16x8 bpre1 = *(const bf16x8*)(WaT + (size_t)(cw0 + 16 + l15) * K + lq * 8);
    __syncthreads();

    // ---- single-pass gather, full-row 2-deep pipeline ----
    {
        constexpr int NSEG = K / 8;         // k-values per thread (32 or 16)
        const int gr = tid >> 3, gseg = tid & 7;
        const int node = bm0 + gr;
        const int nn = cnt[node], rp = rowptr[node];
        const int jbase = rp - rp0;
        const int nIt = nn + 1;             // iteration 0 = own row

        float acc[NSEG];
#pragma unroll
        for (int i = 0; i < NSEG; ++i) acc[i] = 0.f;

        // row index for iteration u: u==0 -> node, else neighbor u-1
        int i1 = (1 < nIt) ? ((jbase + 0 < CCAP) ? colLDS[jbase + 0] : col[rp + 0]) : node;
        int i2 = (2 < nIt) ? ((jbase + 1 < CCAP) ? colLDS[jbase + 1] : col[rp + 1]) : node;

        if (F32SRC) {
            constexpr int NF4 = NSEG / 4;   // float4 per row-chunk
            const float4* bp = (const float4*)hsrc;
            const int stride = K / 4, off = gseg * NF4;
            const float4* pA = bp + (size_t)node * stride + off;
            const float4* pB = bp + (size_t)i1  * stride + off;
            const float4* pC = bp + (size_t)i2  * stride + off;
            float4 A[NF4], B[NF4];
#pragma unroll
            for (int c4 = 0; c4 < NF4; ++c4) { A[c4] = pA[c4]; B[c4] = pB[c4]; }
            for (int t = 0; t < nIt; ++t) {
                float4 C[NF4];
#pragma unroll
                for (int c4 = 0; c4 < NF4; ++c4) C[c4] = pC[c4];
                const int u = t + 3;
                int idxN = node;
                if (u < nIt) idxN = (jbase + u - 1 < CCAP) ? colLDS[jbase + u - 1] : col[rp + u - 1];
                pC = bp + (size_t)idxN * stride + off;
#pragma unroll
                for (int c4 = 0; c4 < NF4; ++c4) {
                    if (RELU) {
                        acc[c4 * 4 + 0] += fmaxf(A[c4].x, 0.f);
                        acc[c4 * 4 + 1] += fmaxf(A[c4].y, 0.f);
                        acc[c4 * 4 + 2] += fmaxf(A[c4].z, 0.f);
                        acc[c4 * 4 + 3] += fmaxf(A[c4].w, 0.f);
                    } else {
                        acc[c4 * 4 + 0] += A[c4].x;
                        acc[c4 * 4 + 1] += A[c4].y;
                        acc[c4 * 4 + 2] += A[c4].z;
                        acc[c4 * 4 + 3] += A[c4].w;
                    }
                }
#pragma unroll
                for (int c4 = 0; c4 < NF4; ++c4) { A[c4] = B[c4]; B[c4] = C[c4]; }
            }
        } else {
            constexpr int NU4 = NSEG / 8;   // uint4 per row-chunk
            const uint4* bp = (const uint4*)hsrc;
            const int stride = K / 8, off = gseg * NU4;
            const uint4* pA = bp + (size_t)node * stride + off;
            const uint4* pB = bp + (size_t)i1  * stride + off;
            const uint4* pC = bp + (size_t)i2  * stride + off;
            uint4 A[NU4], B[NU4];
#pragma unroll
            for (int c4 = 0; c4 < NU4; ++c4) { A[c4] = pA[c4]; B[c4] = pB[c4]; }
            for (int t = 0; t < nIt; ++t) {
                uint4 C[NU4];
#pragma unroll
                for (int c4 = 0; c4 < NU4; ++c4) C[c4] = pC[c4];
                const int u = t + 3;
                int idxN = node;
                if (u < nIt) idxN = (jbase + u - 1 < CCAP) ? colLDS[jbase + u - 1] : col[rp + u - 1];
                pC = bp + (size_t)idxN * stride + off;
#pragma unroll
                for (int c4 = 0; c4 < NU4; ++c4) {
                    u16 vs[8] __attribute__((aligned(16)));
                    *(uint4*)vs = A[c4];
#pragma unroll
                    for (int i2b = 0; i2b < 8; ++i2b) {
                        float x = b2f(vs[i2b]);
                        acc[c4 * 8 + i2b] += RELU ? fmaxf(x, 0.f) : x;
                    }
                }
#pragma unroll
                for (int c4 = 0; c4 < NU4; ++c4) { A[c4] = B[c4]; B[c4] = C[c4]; }
            }
        }

        // write to AH (swizzled blocked MFMA-A layout) via cvt_pk
        const int k0 = gseg * NSEG;
        constexpr int NKC = NSEG / 8;       // 16B chunks (4 or 2)
#pragma unroll
        for (int cc = 0; cc < NKC; ++cc) {
            const int k = k0 + cc * 8;
            const int s  = (k >> 5) * 256 + (gr >> 4) * 64 + ((k >> 3) & 3) * 16 + (gr & 15);
            const int sp = s ^ ((k >> 5) & 7);
            uint4 pk;
            pk.x = cvtpk(acc[cc * 8 + 0], acc[cc * 8 + 1]);
            pk.y = cvtpk(acc[cc * 8 + 2], acc[cc * 8 + 3]);
            pk.z = cvtpk(acc[cc * 8 + 4], acc[cc * 8 + 5]);
            pk.w = cvtpk(acc[cc * 8 + 6], acc[cc * 8 + 7]);
            *(uint4*)(AH + sp * 8) = pk;
        }
    }
    __syncthreads();                              // AH (Aeff) ready

    // ---- phase 1: hidden = relu(Aeff @ Wa + ba); B direct-to-reg ----
    constexpr int NK1 = K / 32;
    f32x4 acc1[4][2];
#pragma unroll
    for (int r = 0; r < 4; ++r)
#pragma unroll
        for (int c = 0; c < 2; ++c) acc1[r][c] = (f32x4){0.f, 0.f, 0.f, 0.f};

#pragma unroll
    for (int kb = 0; kb < NK1; ++kb) {
        bf16x8 a[4], b[2];
        if (kb == 0) { b[0] = bpre0; b[1] = bpre1; }
        else {
#pragma unroll
            for (int c = 0; c < 2; ++c)
                b[c] = *(const bf16x8*)(WaT + (size_t)(cw0 + c * 16 + l15) * K + kb * 32 + lq * 8);
        }
#pragma unroll
        for (int r = 0; r < 4; ++r)
            a[r] = *(const bf16x8*)&AH[(kb * 256 + r * 64 + (lane ^ (kb & 7))) * 8];
        __builtin_amdgcn_s_setprio(1);
#pragma unroll
        for (int r = 0; r < 4; ++r)
#pragma unroll
            for (int c = 0; c < 2; ++c)
                acc1[r][c] = __builtin_amdgcn_mfma_f32_16x16x32_bf16(a[r], b[c], acc1[r][c], 0, 0, 0);
        __builtin_amdgcn_s_setprio(0);
    }
    __syncthreads();                              // all waves done reading Aeff

    // epilogue 1 -> AH (swizzled phase-2 A layout)
    // C/D layout: col = lane&15 (=lc), row = (lane>>4)*4 + i (=lr+i)
#pragma unroll
    for (int c = 0; c < 2; ++c) {
        const int n = cw0 + c * 16 + lc;           // hidden col = phase-2 k
        const float bv = ba[n];
        const int nb = (n >> 5) * 256 + ((n >> 3) & 3) * 16;
        const int sx = (n >> 5) & 7;
#pragma unroll
        for (int r = 0; r < 4; ++r)
#pragma unroll
            for (int i = 0; i < 4; ++i) {
                const int sp = (nb + r * 64 + lr + i) ^ sx;
                AH[sp * 8 + (n & 7)] = f2b(fmaxf(acc1[r][c][i] + bv, 0.f));
            }
    }
    __syncthreads();                              // hidden ready

    // ---- phase 2: out = hidden @ Wb + bb; B direct-to-reg ----
    f32x4 acc2[4][2];
#pragma unroll
    for (int r = 0; r < 4; ++r)
#pragma unroll
        for (int c = 0; c < 2; ++c) acc2[r][c] = (f32x4){0.f, 0.f, 0.f, 0.f};

#pragma unroll
    for (int kb = 0; kb < 8; ++kb) {
        bf16x8 a[4], b[2];
#pragma unroll
        for (int c = 0; c < 2; ++c)
            b[c] = *(const bf16x8*)(WbT + (size_t)(cw0 + c * 16 + l15) * 256 + kb * 32 + lq * 8);
#pragma unroll
        for (int r = 0; r < 4; ++r)
            a[r] = *(const bf16x8*)&AH[(kb * 256 + r * 64 + (lane ^ (kb & 7))) * 8];
        __builtin_amdgcn_s_setprio(1);
#pragma unroll
        for (int r = 0; r < 4; ++r)
#pragma unroll
            for (int c = 0; c < 2; ++c)
                acc2[r][c] = __builtin_amdgcn_mfma_f32_16x16x32_bf16(a[r], b[c], acc2[r][c], 0, 0, 0);
        __builtin_amdgcn_s_setprio(0);
    }
#pragma unroll
    for (int c = 0; c < 2; ++c) {
        const int n = cw0 + c * 16 + lc;
        const float bv = bb[n];
#pragma unroll
        for (int r = 0; r < 4; ++r)
#pragma unroll
            for (int i = 0; i < 4; ++i)
                Hout[(size_t)(bm0 + r * 16 + lr + i) * 256 + n] = f2b(acc2[r][c][i] + bv);
    }
}

// ---------------------------------------------------------------------------
// Classifier linear: C[f32] = leaky(A[bf16] @ WT^T), N=512 via 2 n-blocks.
// ---------------------------------------------------------------------------
__global__ __launch_bounds__(256)
void k_lin(const u16* __restrict__ A, const u16* __restrict__ WT,
           float* __restrict__ C)
{
    __shared__ u16 As[64 * 40];
    __shared__ u16 Bs[256 * 40];
    const int tid = threadIdx.x, lane = tid & 63, wave = tid >> 6;
    const int bm0 = blockIdx.x * 64, bn0 = blockIdx.y * 256;
    const int fm = lane & 15, fk = (lane >> 4) * 8;
    const int lc = lane & 15, lr = (lane >> 4) * 4;
    const int cw0 = wave * 64;
    const int sr = tid >> 2, sc = tid & 3;

    f32x4 acc[4][4];
#pragma unroll
    for (int r = 0; r < 4; ++r)
#pragma unroll
        for (int c = 0; c < 4; ++c) acc[r][c] = (f32x4){0.f, 0.f, 0.f, 0.f};

    for (int k0 = 0; k0 < 256; k0 += 32) {
        *(uint4*)&As[sr * 40 + sc * 8] =
            *(const uint4*)(A + (size_t)(bm0 + sr) * 256 + k0 + sc * 8);
        {
            const uint4* wp = (const uint4*)(WT + (size_t)(bn0 + tid) * 256 + k0);
#pragma unroll
            for (int c = 0; c < 4; ++c)
                *(uint4*)&Bs[tid * 40 + c * 8] = wp[c];
        }
        __syncthreads();
        bf16x8 a[4], b[4];
#pragma unroll
        for (int r = 0; r < 4; ++r) a[r] = *(const bf16x8*)&As[(r * 16 + fm) * 40 + fk];
#pragma unroll
        for (int c = 0; c < 4; ++c) b[c] = *(const bf16x8*)&Bs[(cw0 + c * 16 + fm) * 40 + fk];
#pragma unroll
        for (int r = 0; r < 4; ++r)
#pragma unroll
            for (int c = 0; c < 4; ++c)
                acc[r][c] = __builtin_amdgcn_mfma_f32_16x16x32_bf16(a[r], b[c], acc[r][c], 0, 0, 0);
        __syncthreads();
    }
#pragma unroll
    for (int c = 0; c < 4; ++c) {
        const int col = bn0 + cw0 + c * 16 + lc;
#pragma unroll
        for (int r = 0; r < 4; ++r)
#pragma unroll
            for (int i = 0; i < 4; ++i) {
                float v = acc[r][c][i];
                v = (v >= 0.f) ? v : 0.01f * v;   // leaky
                C[(size_t)(bm0 + r * 16 + lr + i) * 512 + col] = v;
            }
    }
}

// ---------------------------------------------------------------------------
// Head kernels (f32)
// ---------------------------------------------------------------------------
__global__ void k_pool(const u16* __restrict__ H, u16* __restrict__ Xc)
{
    int c = blockIdx.x, f = threadIdx.x;          // 8192 blocks x 256
    const u16* p = H + (size_t)c * 25 * 256 + f;
    float s = 0.f;
#pragma unroll
    for (int j = 0; j < 25; ++j) s += b2f(p[j * 256]);
    Xc[(size_t)c * 256 + f] = f2b(s / 25.0f);
}

// fused set-pool + fc1: Tp[b][s] = sum_c max_m T[b*2+c][m*64+s];
// T1[b][j] = b[j] + sum_k Tp[b][k] * w[k][j].  (identical op order)
__global__ __launch_bounds__(256)
void k_sf(const float* __restrict__ T, const float* __restrict__ w,
          const float* __restrict__ b, float* __restrict__ T1)
{
    __shared__ float tp[8][64];
    const int gl = threadIdx.x >> 5, j = threadIdx.x & 31;   // 8 graphs/block
    const int g = blockIdx.x * 8 + gl;
#pragma unroll
    for (int h = 0; h < 2; ++h) {
        const int s = j + h * 32;
        float acc = 0.f;
#pragma unroll
        for (int c = 0; c < 2; ++c) {
            const float* row = T + ((size_t)(g * 2 + c)) * 512 + s;
            float mx = row[0];
#pragma unroll
            for (int m = 1; m < 8; ++m) mx = fmaxf(mx, row[m * 64]);
            acc += mx;
        }
        tp[gl][s] = acc;
    }
    __syncthreads();
    float sum = b[j];
#pragma unroll
    for (int k = 0; k < 64; ++k) sum += tp[gl][k] * w[k * 32 + j];
    T1[g * 32 + j] = sum;
}

__global__ void k_bnstats(const float* __restrict__ T1, float* __restrict__ stats)
{
    __shared__ float r1[256], r2[256];
    const int j = blockIdx.x, t = threadIdx.x;    // 32 blocks
    float s = 0.f, ss = 0.f;
    for (int b = t; b < 4096; b += 256) {
        float v = T1[b * 32 + j];
        s += v; ss += v * v;
    }
    r1[t] = s; r2[t] = ss;
    __syncthreads();
    for (int off = 128; off > 0; off >>= 1) {
        if (t < off) { r1[t] += r1[t + off]; r2[t] += r2[t + off]; }
        __syncthreads();
    }
    if (t == 0) {
        float mu  = r1[0] * (1.f / 4096.f);
        float var = r2[0] * (1.f / 4096.f) - mu * mu;
        stats[j]      = mu;
        stats[32 + j] = 1.f / sqrtf(var + 1e-5f);
    }
}

__global__ void k_head(const float* __restrict__ T1, const float* __restrict__ stats,
                       const float* __restrict__ g, const float* __restrict__ bb,
                       const float* __restrict__ w2, const float* __restrict__ b2,
                       float* __restrict__ out)
{
    const int b = blockIdx.x * 256 + threadIdx.x; // 4096
    float l0 = b2[0], l1 = b2[1];
#pragma unroll
    for (int j = 0; j < 32; ++j) {
        float v = (T1[b * 32 + j] - stats[j]) * stats[32 + j] * g[j] + bb[j];
        v = (v >= 0.f) ? v : 0.01f * v;
        l0 += v * w2[j * 2];
        l1 += v * w2[j * 2 + 1];
    }
    float mx  = fmaxf(l0, l1);
    float lse = mx + logf(expf(l0 - mx) + expf(l1 - mx));
    out[b * 2]     = l0 - lse;
    out[b * 2 + 1] = l1 - lse;
}

// ---------------------------------------------------------------------------
extern "C" void kernel_launch(void* const* d_in, const int* in_sizes, int n_in,
                              void* d_out, int out_size, void* d_ws, size_t ws_size,
                              hipStream_t stream)
{
    (void)n_in; (void)out_size; (void)ws_size;
    constexpr int NN = 204800, NCOMP = 8192, NGRAPH = 4096;

    const float* x    = (const float*)d_in[0];
    const float* w0a  = (const float*)d_in[1];
    const float* b0a  = (const float*)d_in[2];
    const float* w0b  = (const float*)d_in[3];
    const float* b0b  = (const float*)d_in[4];
    const float* wra  = (const float*)d_in[5];
    const float* bra  = (const float*)d_in[6];
    const float* wrb  = (const float*)d_in[7];
    const float* brb  = (const float*)d_in[8];
    const float* Wc   = (const float*)d_in[9];
    const float* f1w  = (const float*)d_in[10];
    const float* f1b  = (const float*)d_in[11];
    const float* bng  = (const float*)d_in[12];
    const float* bnb  = (const float*)d_in[13];
    const float* f2w  = (const float*)d_in[14];
    const float* f2bb = (const float*)d_in[15];
    const int* ei   = (const int*)d_in[16];
    const int  E    = in_sizes[16] / 2;           // 409600
    const int* src  = ei;
    const int* dst  = ei + E;

    // ---- workspace layout (~215 MiB) ----
    char* ws = (char*)d_ws;
    u16*    H1  = (u16*)ws;                                  // [N,256] bf16 ping
    u16*    H0  = (u16*)(ws + (size_t)104857600);            // [N,256] bf16 pong (final)
    u16*    wt  = (u16*)(ws + (size_t)209715200);            // transposed bf16 weights, 1 MiB
    u16 *WT0 = wt, *WT1 = wt + 65536, *WT2 = wt + 131072, *WT3 = wt + 196608,
        *WT4 = wt + 262144, *WT5 = wt + 327680, *WT6 = wt + 393216;
    // CSR arrays after weights:
    char* csr = ws + (size_t)210763776;
    int* cnt    = (int*)csr;                                 // [N]
    int* rowptr = (int*)(csr + 819200);                      // [N]
    int* cursor = (int*)(csr + 1638400);                     // [N]
    int* col    = (int*)(csr + 2457600);                     // [E]
    int* bsum   = (int*)(csr + 4096000);                     // [1024]
    int* bscan  = (int*)(csr + 4100096);                     // [1024]
    // head scratch reuses dead H1 region:
    u16*   Xc    = (u16*)ws;                                 // [8192,256] bf16
    float* Tfull = (float*)(ws + (size_t)16777216);          // [8192,512] f32
    float* T1    = (float*)(ws + (size_t)41943040);          // [4096,32]
    float* stats = (float*)(ws + (size_t)46137344);          // mu[32], rstd[32]

    const dim3 blk(256);
    const dim3 blk512(512);
    const int NB = NN / 256;                                  // 800 scan blocks

    // ---- setup: counts + all weight transposes in one launch ----
    hipMemsetAsync(cnt, 0, NN * 4, stream);
    k_setup<<<1920, blk, 0, stream>>>(w0a, w0b, wra, wrb, Wc, wt, dst, cnt, E);
    k_scan1<<<NB, blk, 0, stream>>>(cnt, rowptr, bsum, NN);
    k_scan2<<<1, blk, 0, stream>>>(bsum, bscan, NB);
    k_scan3<<<NB, blk, 0, stream>>>(rowptr, bscan, cursor, NN);
    k_fill<<<(E + 255) / 256, blk, 0, stream>>>(src, dst, cursor, col, E);

    // ---- fused GIN layers (aggregation inside k_gin; H ping-pongs) ----
    // layer 0: src = x (f32, K=128, no relu) -> H0
    k_gin<128, false, true><<<NN / 64, blk512, 0, stream>>>(
        x, cnt, rowptr, col, WT0, b0a, WT1, b0b, H0, NN, E);
    // layer 1: src = H0 (bf16, relu) -> H1
    k_gin<256, true, false><<<NN / 64, blk512, 0, stream>>>(
        H0, cnt, rowptr, col, WT2, bra, WT4, brb, H1, NN, E);
    // layer 2: src = H1 (bf16, relu) -> H0
    k_gin<256, true, false><<<NN / 64, blk512, 0, stream>>>(
        H1, cnt, rowptr, col, WT3, bra + 256, WT5, brb + 256, H0, NN, E);

    // ---- head ----
    k_pool<<<NCOMP, blk, 0, stream>>>(H0, Xc);
    k_lin<<<dim3(NCOMP / 64, 2), blk, 0, stream>>>(Xc, WT6, Tfull);
    k_sf<<<NGRAPH / 8, blk, 0, stream>>>(Tfull, f1w, f1b, T1);
    k_bnstats<<<32, blk, 0, stream>>>(T1, stats);
    k_head<<<NGRAPH / 256, blk, 0, stream>>>(T1, stats, bng, bnb, f2w, f2bb, (float*)d_out);
}

// Round 10
// 684.087 us; speedup vs baseline: 1.4889x; 1.4889x over previous
//
#include <hip/hip_runtime.h>
#include <hip/hip_fp16.h>
#include <math.h>

typedef unsigned short u16;
typedef float f32x4 __attribute__((ext_vector_type(4)));
typedef __bf16 bf16x8 __attribute__((ext_vector_type(8)));

__device__ __forceinline__ float b2f(u16 u) {
    union { unsigned int i; float f; } v; v.i = ((unsigned int)u) << 16; return v.f;
}
__device__ __forceinline__ u16 f2b(float f) {
    union { float f; unsigned int i; } v; v.f = f;
    unsigned int lsb = (v.i >> 16) & 1u;
    return (u16)((v.i + 0x7fffu + lsb) >> 16);   // RNE
}
// HW RNE pack: low16 = bf16(lo), high16 = bf16(hi). Bit-identical to f2b.
__device__ __forceinline__ unsigned int cvtpk(float lo, float hi) {
    unsigned int r;
    asm("v_cvt_pk_bf16_f32 %0, %1, %2" : "=v"(r) : "v"(lo), "v"(hi));
    return r;
}

// ---------------------------------------------------------------------------
// CSR build: counts -> block scan -> global scan -> fill
// ---------------------------------------------------------------------------
__global__ __launch_bounds__(256)
void k_scan1(const int* __restrict__ cnt, int* __restrict__ rowptr,
             int* __restrict__ bsum, int N)
{
    __shared__ int s[256];
    int t = threadIdx.x, i = blockIdx.x * 256 + t;
    int v = (i < N) ? cnt[i] : 0;
    s[t] = v;
    __syncthreads();
#pragma unroll
    for (int off = 1; off < 256; off <<= 1) {
        int add = (t >= off) ? s[t - off] : 0;
        __syncthreads();
        s[t] += add;
        __syncthreads();
    }
    if (i < N) rowptr[i] = s[t] - v;
    if (t == 255) bsum[blockIdx.x] = s[255];
}

__global__ __launch_bounds__(256)
void k_scan2(const int* __restrict__ bsum, int* __restrict__ bscan, int nb)
{
    __shared__ int s[256];
    int t = threadIdx.x;
    int g[4], e[4];
    int base = t * 4;
#pragma unroll
    for (int j = 0; j < 4; ++j) g[j] = (base + j < nb) ? bsum[base + j] : 0;
    e[0] = 0; e[1] = g[0]; e[2] = g[0] + g[1]; e[3] = g[0] + g[1] + g[2];
    int tsum = e[3] + g[3];
    s[t] = tsum;
    __syncthreads();
#pragma unroll
    for (int off = 1; off < 256; off <<= 1) {
        int add = (t >= off) ? s[t - off] : 0;
        __syncthreads();
        s[t] += add;
        __syncthreads();
    }
    int texcl = s[t] - tsum;
#pragma unroll
    for (int j = 0; j < 4; ++j)
        if (base + j < nb) bscan[base + j] = texcl + e[j];
}

__global__ __launch_bounds__(256)
void k_scan3(int* __restrict__ rowptr, const int* __restrict__ bscan,
             int* __restrict__ cursor, int N)
{
    int i = blockIdx.x * 256 + threadIdx.x;
    if (i >= N) return;
    int r = rowptr[i] + bscan[i >> 8];
    rowptr[i] = r;
    cursor[i] = r;
}

__global__ __launch_bounds__(256)
void k_fill(const int* __restrict__ src, const int* __restrict__ dst,
            int* __restrict__ cursor, int* __restrict__ col, int E)
{
    int e = blockIdx.x * 256 + threadIdx.x;
    if (e >= E) return;
    int pos = atomicAdd(&cursor[dst[e]], 1);
    col[pos] = src[e];
}

// ---------------------------------------------------------------------------
// Fused setup: edge counting + all 7 weight transposes (f32->bf16) in ONE
// launch. Grid = 1920 blocks x 256 (491520 transpose elems >= 409600 edges).
// ---------------------------------------------------------------------------
__global__ __launch_bounds__(256)
void k_setup(const float* __restrict__ w0a, const float* __restrict__ w0b,
             const float* __restrict__ wra, const float* __restrict__ wrb,
             const float* __restrict__ Wc,  u16* __restrict__ wt,
             const int* __restrict__ dst, int* __restrict__ cnt, int E)
{
    int t = blockIdx.x * 256 + threadIdx.x;
    if (t < E) atomicAdd(&cnt[dst[t]], 1);

    const float* in; u16* out; int K, N, l;
    if      (t < 32768)  { in = w0a;          out = wt;          K = 128; N = 256; l = t; }
    else if (t < 98304)  { in = w0b;          out = wt + 65536;  K = 256; N = 256; l = t - 32768; }
    else if (t < 163840) { in = wra;          out = wt + 131072; K = 256; N = 256; l = t - 98304; }
    else if (t < 229376) { in = wra + 65536;  out = wt + 196608; K = 256; N = 256; l = t - 163840; }
    else if (t < 294912) { in = wrb;          out = wt + 262144; K = 256; N = 256; l = t - 229376; }
    else if (t < 360448) { in = wrb + 65536;  out = wt + 327680; K = 256; N = 256; l = t - 294912; }
    else if (t < 491520) { in = Wc;           out = wt + 393216; K = 256; N = 512; l = t - 360448; }
    else return;
    out[l] = f2b(in[(l % K) * N + l / K]);
}

// ---------------------------------------------------------------------------
// Fused GIN layer v10 = v8 (best measured) + LAST variant that fuses the
// per-component mean pooling: instead of writing H (102 MB) for k_pool to
// re-read (105 MB), stage bf16 outputs in AH and atomically accumulate
// per-component f32 partial sums into Xcf[8192][256].
//
// v8 structure: 512 thr, 64 rows/block, 8 waves. Gather: 8 thr/node,
// single pass, contiguous 64B/thread, 1-deep half-row pipeline, colLDS.
// GEMM: 8 waves x (64x32), acc[4][2], B direct-to-reg, swizzled AH.
// ---------------------------------------------------------------------------
#define CCAP 512

template<int K, bool RELU, bool F32SRC, bool LAST>
__global__ __launch_bounds__(512, 6)
void k_gin(const void* __restrict__ hsrc,
           const int* __restrict__ cnt, const int* __restrict__ rowptr,
           const int* __restrict__ col,
           const u16* __restrict__ WaT, const float* __restrict__ ba,
           const u16* __restrict__ WbT, const float* __restrict__ bb,
           u16* __restrict__ Hout, float* __restrict__ Xcf, int Ntot, int Etot)
{
    __shared__ u16 AH[64 * 256];     // 32 KB = 2048 slots of 16B
    __shared__ int colLDS[CCAP];     //  2 KB

    const int tid = threadIdx.x, lane = tid & 63, wave = tid >> 6;
    const int bm0 = blockIdx.x * 64;
    const int lc = lane & 15, lr = (lane >> 4) * 4;
    const int cw0 = wave * 32;                    // this wave's 32 output cols
    const int l15 = lane & 15, lq = lane >> 4;

    // ---- stage block's col slice into LDS (coalesced) ----
    const int rp0 = rowptr[bm0];
    const int rpE = (bm0 + 64 < Ntot) ? rowptr[bm0 + 64] : Etot;
    const int total = rpE - rp0;
    for (int i = tid; i < total && i < CCAP; i += 512) colLDS[i] = col[rp0 + i];

    // prefetch phase-1 B fragments for kb=0 (independent of gather)
    bf16x8 bpre0 = *(const bf16x8*)(WaT + (size_t)(cw0 + l15) * K + lq * 8);
    bf16x8 bpre1 = *(const bf16x8*)(WaT + (size_t)(cw0 + 16 + l15) * K + lq * 8);
    __syncthreads();

    // ---- single-pass pipelined gather into AH (v8) ----
    {
        constexpr int NSEG = K / 8;         // k-values per thread (32 or 16)
        const int gr = tid >> 3, gseg = tid & 7;
        const int node = bm0 + gr;
        const int nn = cnt[node], rp = rowptr[node];
        const int jbase = rp - rp0;
        const int nIt = nn + 1;             // item 0 = own row

        float acc[NSEG];
#pragma unroll
        for (int i = 0; i < NSEG; ++i) acc[i] = 0.f;

        if (F32SRC) {
            const float4* bp = (const float4*)hsrc;
            const int stride = K / 4, off = gseg * (NSEG / 4);
            const float4* p = bp + (size_t)node * stride + off;
            float4 a0 = p[0], a1 = p[1];
            for (int t = 0; t < nIt; ++t) {
                float4 b0 = p[2], b1 = p[3];
                int tn = (t + 1 < nIt) ? t + 1 : t;
                int jl = jbase + tn - 1;
                int idxN = (tn == 0) ? node : ((jl < CCAP) ? colLDS[jl] : col[rp + tn - 1]);
                const float4* q = bp + (size_t)idxN * stride + off;
                float4 n0 = q[0], n1 = q[1];
                if (RELU) {
                    acc[0] += fmaxf(a0.x,0.f); acc[1] += fmaxf(a0.y,0.f); acc[2] += fmaxf(a0.z,0.f); acc[3] += fmaxf(a0.w,0.f);
                    acc[4] += fmaxf(a1.x,0.f); acc[5] += fmaxf(a1.y,0.f); acc[6] += fmaxf(a1.z,0.f); acc[7] += fmaxf(a1.w,0.f);
                    acc[8] += fmaxf(b0.x,0.f); acc[9] += fmaxf(b0.y,0.f); acc[10]+= fmaxf(b0.z,0.f); acc[11]+= fmaxf(b0.w,0.f);
                    acc[12]+= fmaxf(b1.x,0.f); acc[13]+= fmaxf(b1.y,0.f); acc[14]+= fmaxf(b1.z,0.f); acc[15]+= fmaxf(b1.w,0.f);
                } else {
                    acc[0] += a0.x; acc[1] += a0.y; acc[2] += a0.z; acc[3] += a0.w;
                    acc[4] += a1.x; acc[5] += a1.y; acc[6] += a1.z; acc[7] += a1.w;
                    acc[8] += b0.x; acc[9] += b0.y; acc[10]+= b0.z; acc[11]+= b0.w;
                    acc[12]+= b1.x; acc[13]+= b1.y; acc[14]+= b1.z; acc[15]+= b1.w;
                }
                a0 = n0; a1 = n1; p = q;
            }
        } else {
            const uint4* bp = (const uint4*)hsrc;
            const int stride = K / 8, off = gseg * (NSEG / 8);
            const uint4* p = bp + (size_t)node * stride + off;
            uint4 a0 = p[0], a1 = p[1];
            for (int t = 0; t < nIt; ++t) {
                uint4 b0 = p[2], b1 = p[3];
                int tn = (t + 1 < nIt) ? t + 1 : t;
                int jl = jbase + tn - 1;
                int idxN = (tn == 0) ? node : ((jl < CCAP) ? colLDS[jl] : col[rp + tn - 1]);
                const uint4* q = bp + (size_t)idxN * stride + off;
                uint4 n0 = q[0], n1 = q[1];
                u16 vs[32] __attribute__((aligned(16)));
                *(uint4*)(vs + 0)  = a0; *(uint4*)(vs + 8)  = a1;
                *(uint4*)(vs + 16) = b0; *(uint4*)(vs + 24) = b1;
#pragma unroll
                for (int i2 = 0; i2 < 32; ++i2) {
                    float x = b2f(vs[i2]);
                    acc[i2] += RELU ? fmaxf(x, 0.f) : x;
                }
                a0 = n0; a1 = n1; p = q;
            }
        }

        // write to AH (swizzled blocked MFMA-A layout) via cvt_pk
        const int k0 = gseg * NSEG;
        constexpr int NKC = NSEG / 8;       // 16B chunks (4 or 2)
#pragma unroll
        for (int cc = 0; cc < NKC; ++cc) {
            const int k = k0 + cc * 8;
            const int s  = (k >> 5) * 256 + (gr >> 4) * 64 + ((k >> 3) & 3) * 16 + (gr & 15);
            const int sp = s ^ ((k >> 5) & 7);
            uint4 pk;
            pk.x = cvtpk(acc[cc * 8 + 0], acc[cc * 8 + 1]);
            pk.y = cvtpk(acc[cc * 8 + 2], acc[cc * 8 + 3]);
            pk.z = cvtpk(acc[cc * 8 + 4], acc[cc * 8 + 5]);
            pk.w = cvtpk(acc[cc * 8 + 6], acc[cc * 8 + 7]);
            *(uint4*)(AH + sp * 8) = pk;
        }
    }
    __syncthreads();                              // AH (Aeff) ready

    // ---- phase 1: hidden = relu(Aeff @ Wa + ba); B direct-to-reg ----
    constexpr int NK1 = K / 32;
    f32x4 acc1[4][2];
#pragma unroll
    for (int r = 0; r < 4; ++r)
#pragma unroll
        for (int c = 0; c < 2; ++c) acc1[r][c] = (f32x4){0.f, 0.f, 0.f, 0.f};

#pragma unroll
    for (int kb = 0; kb < NK1; ++kb) {
        bf16x8 a[4], b[2];
        if (kb == 0) { b[0] = bpre0; b[1] = bpre1; }
        else {
#pragma unroll
            for (int c = 0; c < 2; ++c)
                b[c] = *(const bf16x8*)(WaT + (size_t)(cw0 + c * 16 + l15) * K + kb * 32 + lq * 8);
        }
#pragma unroll
        for (int r = 0; r < 4; ++r)
            a[r] = *(const bf16x8*)&AH[(kb * 256 + r * 64 + (lane ^ (kb & 7))) * 8];
        __builtin_amdgcn_s_setprio(1);
#pragma unroll
        for (int r = 0; r < 4; ++r)
#pragma unroll
            for (int c = 0; c < 2; ++c)
                acc1[r][c] = __builtin_amdgcn_mfma_f32_16x16x32_bf16(a[r], b[c], acc1[r][c], 0, 0, 0);
        __builtin_amdgcn_s_setprio(0);
    }
    __syncthreads();                              // all waves done reading Aeff

    // epilogue 1 -> AH (swizzled phase-2 A layout)
    // C/D layout: col = lane&15 (=lc), row = (lane>>4)*4 + i (=lr+i)
#pragma unroll
    for (int c = 0; c < 2; ++c) {
        const int n = cw0 + c * 16 + lc;           // hidden col = phase-2 k
        const float bv = ba[n];
        const int nb = (n >> 5) * 256 + ((n >> 3) & 3) * 16;
        const int sx = (n >> 5) & 7;
#pragma unroll
        for (int r = 0; r < 4; ++r)
#pragma unroll
            for (int i = 0; i < 4; ++i) {
                const int sp = (nb + r * 64 + lr + i) ^ sx;
                AH[sp * 8 + (n & 7)] = f2b(fmaxf(acc1[r][c][i] + bv, 0.f));
            }
    }
    __syncthreads();                              // hidden ready

    // ---- phase 2: out = hidden @ Wb + bb; B direct-to-reg ----
    f32x4 acc2[4][2];
#pragma unroll
    for (int r = 0; r < 4; ++r)
#pragma unroll
        for (int c = 0; c < 2; ++c) acc2[r][c] = (f32x4){0.f, 0.f, 0.f, 0.f};

#pragma unroll
    for (int kb = 0; kb < 8; ++kb) {
        bf16x8 a[4], b[2];
#pragma unroll
        for (int c = 0; c < 2; ++c)
            b[c] = *(const bf16x8*)(WbT + (size_t)(cw0 + c * 16 + l15) * 256 + kb * 32 + lq * 8);
#pragma unroll
        for (int r = 0; r < 4; ++r)
            a[r] = *(const bf16x8*)&AH[(kb * 256 + r * 64 + (lane ^ (kb & 7))) * 8];
        __builtin_amdgcn_s_setprio(1);
#pragma unroll
        for (int r = 0; r < 4; ++r)
#pragma unroll
            for (int c = 0; c < 2; ++c)
                acc2[r][c] = __builtin_amdgcn_mfma_f32_16x16x32_bf16(a[r], b[c], acc2[r][c], 0, 0, 0);
        __builtin_amdgcn_s_setprio(0);
    }

    if (!LAST) {
        // normal epilogue: store H
#pragma unroll
        for (int c = 0; c < 2; ++c) {
            const int n = cw0 + c * 16 + lc;
            const float bv = bb[n];
#pragma unroll
            for (int r = 0; r < 4; ++r)
#pragma unroll
                for (int i = 0; i < 4; ++i)
                    Hout[(size_t)(bm0 + r * 16 + lr + i) * 256 + n] = f2b(acc2[r][c][i] + bv);
        }
    } else {
        // fused component-pool epilogue: stage bf16 rows in AH (dead), then
        // per-component partial sums (row order) -> atomicAdd into Xcf.
        __syncthreads();                          // all phase-2 AH reads done
#pragma unroll
        for (int c = 0; c < 2; ++c) {
            const int n = cw0 + c * 16 + lc;
            const float bv = bb[n];
#pragma unroll
            for (int r = 0; r < 4; ++r)
#pragma unroll
                for (int i = 0; i < 4; ++i)
                    AH[(r * 16 + lr + i) * 256 + n] = f2b(acc2[r][c][i] + bv);
        }
        __syncthreads();
        const int f = tid & 255, h = tid >> 8;
        const int cfirst = bm0 / 25, clast = (bm0 + 63) / 25;
        for (int cc2 = cfirst + h; cc2 <= clast; cc2 += 2) {
            int lo = cc2 * 25 - bm0;      if (lo < 0) lo = 0;
            int hi = cc2 * 25 + 25 - bm0; if (hi > 64) hi = 64;
            float s2 = 0.f;
            for (int r2 = lo; r2 < hi; ++r2) s2 += b2f(AH[r2 * 256 + f]);
            atomicAdd(&Xcf[(size_t)cc2 * 256 + f], s2);
        }
    }
}

// finish pooling: Xc = bf16(Xcf / 25)
__global__ __launch_bounds__(256)
void k_poolfin(const float* __restrict__ Xcf, u16* __restrict__ Xc)
{
    int t = blockIdx.x * 256 + threadIdx.x;       // 2048 blocks, 4 elems/thread
    float4 v = *(const float4*)(Xcf + (size_t)t * 4);
    u16 o[4] __attribute__((aligned(8)));
    o[0] = f2b(v.x / 25.0f); o[1] = f2b(v.y / 25.0f);
    o[2] = f2b(v.z / 25.0f); o[3] = f2b(v.w / 25.0f);
    *(uint2*)(Xc + (size_t)t * 4) = *(const uint2*)o;
}

// ---------------------------------------------------------------------------
// Classifier linear: C[f32] = leaky(A[bf16] @ WT^T), N=512 via 2 n-blocks.
// ---------------------------------------------------------------------------
__global__ __launch_bounds__(256)
void k_lin(const u16* __restrict__ A, const u16* __restrict__ WT,
           float* __restrict__ C)
{
    __shared__ u16 As[64 * 40];
    __shared__ u16 Bs[256 * 40];
    const int tid = threadIdx.x, lane = tid & 63, wave = tid >> 6;
    const int bm0 = blockIdx.x * 64, bn0 = blockIdx.y * 256;
    const int fm = lane & 15, fk = (lane >> 4) * 8;
    const int lc = lane & 15, lr = (lane >> 4) * 4;
    const int cw0 = wave * 64;
    const int sr = tid >> 2, sc = tid & 3;

    f32x4 acc[4][4];
#pragma unroll
    for (int r = 0; r < 4; ++r)
#pragma unroll
        for (int c = 0; c < 4; ++c) acc[r][c] = (f32x4){0.f, 0.f, 0.f, 0.f};

    for (int k0 = 0; k0 < 256; k0 += 32) {
        *(uint4*)&As[sr * 40 + sc * 8] =
            *(const uint4*)(A + (size_t)(bm0 + sr) * 256 + k0 + sc * 8);
        {
            const uint4* wp = (const uint4*)(WT + (size_t)(bn0 + tid) * 256 + k0);
#pragma unroll
            for (int c = 0; c < 4; ++c)
                *(uint4*)&Bs[tid * 40 + c * 8] = wp[c];
        }
        __syncthreads();
        bf16x8 a[4], b[4];
#pragma unroll
        for (int r = 0; r < 4; ++r) a[r] = *(const bf16x8*)&As[(r * 16 + fm) * 40 + fk];
#pragma unroll
        for (int c = 0; c < 4; ++c) b[c] = *(const bf16x8*)&Bs[(cw0 + c * 16 + fm) * 40 + fk];
#pragma unroll
        for (int r = 0; r < 4; ++r)
#pragma unroll
            for (int c = 0; c < 4; ++c)
                acc[r][c] = __builtin_amdgcn_mfma_f32_16x16x32_bf16(a[r], b[c], acc[r][c], 0, 0, 0);
        __syncthreads();
    }
#pragma unroll
    for (int c = 0; c < 4; ++c) {
        const int col = bn0 + cw0 + c * 16 + lc;
#pragma unroll
        for (int r = 0; r < 4; ++r)
#pragma unroll
            for (int i = 0; i < 4; ++i) {
                float v = acc[r][c][i];
                v = (v >= 0.f) ? v : 0.01f * v;   // leaky
                C[(size_t)(bm0 + r * 16 + lr + i) * 512 + col] = v;
            }
    }
}

// ---------------------------------------------------------------------------
// fused set-pool + fc1 + BN-stats accumulation.
// Tp[b][s] = sum_c max_m T[b*2+c][m*64+s]; T1[b][j] = b[j] + sum_k Tp*w.
// Per-block reduction of T1 values -> atomicAdd into stats S[32], SS[32].
// ---------------------------------------------------------------------------
__global__ __launch_bounds__(256)
void k_sf(const float* __restrict__ T, const float* __restrict__ w,
          const float* __restrict__ b, float* __restrict__ T1,
          float* __restrict__ stats)
{
    __shared__ float tp[8][64];
    const int gl = threadIdx.x >> 5, j = threadIdx.x & 31;   // 8 graphs/block
    const int g = blockIdx.x * 8 + gl;
#pragma unroll
    for (int h = 0; h < 2; ++h) {
        const int s = j + h * 32;
        float acc = 0.f;
#pragma unroll
        for (int c = 0; c < 2; ++c) {
            const float* row = T + ((size_t)(g * 2 + c)) * 512 + s;
            float mx = row[0];
#pragma unroll
            for (int m = 1; m < 8; ++m) mx = fmaxf(mx, row[m * 64]);
            acc += mx;
        }
        tp[gl][s] = acc;
    }
    __syncthreads();
    float sum = b[j];
#pragma unroll
    for (int k = 0; k < 64; ++k) sum += tp[gl][k] * w[k * 32 + j];
    T1[g * 32 + j] = sum;
    __syncthreads();                              // tp reads done
    float* red = &tp[0][0];
    red[gl * 32 + j] = sum;
    __syncthreads();
    if (threadIdx.x < 32) {
        float s = 0.f, ss = 0.f;
#pragma unroll
        for (int g2 = 0; g2 < 8; ++g2) {
            float v = red[g2 * 32 + threadIdx.x];
            s += v; ss += v * v;
        }
        atomicAdd(&stats[threadIdx.x], s);
        atomicAdd(&stats[32 + threadIdx.x], ss);
    }
}

__global__ void k_head(const float* __restrict__ T1, const float* __restrict__ stats,
                       const float* __restrict__ g, const float* __restrict__ bb,
                       const float* __restrict__ w2, const float* __restrict__ b2,
                       float* __restrict__ out)
{
    const int b = blockIdx.x * 256 + threadIdx.x; // 4096
    float l0 = b2[0], l1 = b2[1];
#pragma unroll
    for (int j = 0; j < 32; ++j) {
        float mu  = stats[j] * (1.f / 4096.f);
        float var = stats[32 + j] * (1.f / 4096.f) - mu * mu;
        float rstd = 1.f / sqrtf(var + 1e-5f);
        float v = (T1[b * 32 + j] - mu) * rstd * g[j] + bb[j];
        v = (v >= 0.f) ? v : 0.01f * v;
        l0 += v * w2[j * 2];
        l1 += v * w2[j * 2 + 1];
    }
    float mx  = fmaxf(l0, l1);
    float lse = mx + logf(expf(l0 - mx) + expf(l1 - mx));
    out[b * 2]     = l0 - lse;
    out[b * 2 + 1] = l1 - lse;
}

// ---------------------------------------------------------------------------
extern "C" void kernel_launch(void* const* d_in, const int* in_sizes, int n_in,
                              void* d_out, int out_size, void* d_ws, size_t ws_size,
                              hipStream_t stream)
{
    (void)n_in; (void)out_size; (void)ws_size;
    constexpr int NN = 204800, NCOMP = 8192, NGRAPH = 4096;

    const float* x    = (const float*)d_in[0];
    const float* w0a  = (const float*)d_in[1];
    const float* b0a  = (const float*)d_in[2];
    const float* w0b  = (const float*)d_in[3];
    const float* b0b  = (const float*)d_in[4];
    const float* wra  = (const float*)d_in[5];
    const float* bra  = (const float*)d_in[6];
    const float* wrb  = (const float*)d_in[7];
    const float* brb  = (const float*)d_in[8];
    const float* Wc   = (const float*)d_in[9];
    const float* f1w  = (const float*)d_in[10];
    const float* f1b  = (const float*)d_in[11];
    const float* bng  = (const float*)d_in[12];
    const float* bnb  = (const float*)d_in[13];
    const float* f2w  = (const float*)d_in[14];
    const float* f2bb = (const float*)d_in[15];
    const int* ei   = (const int*)d_in[16];
    const int  E    = in_sizes[16] / 2;           // 409600
    const int* src  = ei;
    const int* dst  = ei + E;

    // ---- workspace layout (~215 MiB) ----
    char* ws = (char*)d_ws;
    u16*    H1  = (u16*)ws;                                  // [N,256] bf16 ping
    u16*    H0  = (u16*)(ws + (size_t)104857600);            // [N,256] bf16 pong
    u16*    wt  = (u16*)(ws + (size_t)209715200);            // transposed bf16 weights, 1 MiB
    u16 *WT0 = wt, *WT1 = wt + 65536, *WT2 = wt + 131072, *WT3 = wt + 196608,
        *WT4 = wt + 262144, *WT5 = wt + 327680, *WT6 = wt + 393216;
    // CSR arrays after weights:
    char* csr = ws + (size_t)210763776;
    int* cnt    = (int*)csr;                                 // [N]
    int* rowptr = (int*)(csr + 819200);                      // [N]
    int* cursor = (int*)(csr + 1638400);                     // [N]
    int* col    = (int*)(csr + 2457600);                     // [E]
    int* bsum   = (int*)(csr + 4096000);                     // [1024]
    int* bscan  = (int*)(csr + 4100096);                     // [1024]
    // Xcf reuses H0 region (dead during layer 2); head scratch reuses H1:
    float* Xcf   = (float*)(ws + (size_t)104857600);         // [8192,256] f32, 8 MB
    u16*   Xc    = (u16*)ws;                                 // [8192,256] bf16
    float* Tfull = (float*)(ws + (size_t)16777216);          // [8192,512] f32
    float* T1    = (float*)(ws + (size_t)41943040);          // [4096,32]
    float* stats = (float*)(ws + (size_t)46137344);          // S[32], SS[32]

    const dim3 blk(256);
    const dim3 blk512(512);
    const int NB = NN / 256;                                  // 800 scan blocks

    // ---- setup: counts + all weight transposes in one launch ----
    hipMemsetAsync(cnt, 0, NN * 4, stream);
    k_setup<<<1920, blk, 0, stream>>>(w0a, w0b, wra, wrb, Wc, wt, dst, cnt, E);
    k_scan1<<<NB, blk, 0, stream>>>(cnt, rowptr, bsum, NN);
    k_scan2<<<1, blk, 0, stream>>>(bsum, bscan, NB);
    k_scan3<<<NB, blk, 0, stream>>>(rowptr, bscan, cursor, NN);
    k_fill<<<(E + 255) / 256, blk, 0, stream>>>(src, dst, cursor, col, E);

    // ---- fused GIN layers ----
    // layer 0: src = x (f32, K=128, no relu) -> H0
    k_gin<128, false, true, false><<<NN / 64, blk512, 0, stream>>>(
        x, cnt, rowptr, col, WT0, b0a, WT1, b0b, H0, nullptr, NN, E);
    // layer 1: src = H0 (bf16, relu) -> H1
    k_gin<256, true, false, false><<<NN / 64, blk512, 0, stream>>>(
        H0, cnt, rowptr, col, WT2, bra, WT4, brb, H1, nullptr, NN, E);
    // H0 now dead -> its region becomes Xcf; zero it, then layer 2 fuses pooling
    hipMemsetAsync(Xcf, 0, (size_t)NCOMP * 256 * 4, stream);
    k_gin<256, true, false, true><<<NN / 64, blk512, 0, stream>>>(
        H1, cnt, rowptr, col, WT3, bra + 256, WT5, brb + 256, nullptr, Xcf, NN, E);

    // ---- head ----
    k_poolfin<<<(NCOMP * 256 / 4) / 256, blk, 0, stream>>>(Xcf, Xc);
    k_lin<<<dim3(NCOMP / 64, 2), blk, 0, stream>>>(Xc, WT6, Tfull);
    hipMemsetAsync(stats, 0, 256, stream);
    k_sf<<<NGRAPH / 8, blk, 0, stream>>>(Tfull, f1w, f1b, T1, stats);
    k_head<<<NGRAPH / 256, blk, 0, stream>>>(T1, stats, bng, bnb, f2w, f2bb, (float*)d_out);
}